// Round 4
// baseline (475.575 us; speedup 1.0000x reference)
//
#include <hip/hip_runtime.h>
#include <stdint.h>

// ---------------------------------------------------------------------------
// ShiftedWindowAttention: B=32, H=W=64, C=256, heads=8, hd=32, ws=8, shift=4.
// Pipeline (v4):
//   cvtw (weights f32->bf16, merged wqkv+wout)
//   bias (pos_enc -> transposed/interleaved bias+mask table, f32)
//   qkv  (FUSED cvtx+GEMM; resident 64KB LDS A staged once; B fragments loaded
//         GLOBAL->VGPR directly (wq is L2-resident) -> no dbuf, no K-loop
//         barriers, LDS pipe load cut ~60%; 2KB/wave epilogue slices)
//   attn (per-(window,head) wave, unchanged)
//   oproj(GEMM 131072x256x256; BOTH operand fragments global->VGPR, zero LDS,
//         zero barriers, n-loop internal so AO fetched once)
// ---------------------------------------------------------------------------

typedef short short8 __attribute__((ext_vector_type(8)));
typedef short s16x4 __attribute__((ext_vector_type(4)));
typedef float f32x4 __attribute__((ext_vector_type(4)));

#define SCALE 0.17677669529663687f

__device__ __forceinline__ uint16_t f2bf(float f) {
  union { float f; uint32_t u; } c; c.f = f;
  uint32_t r = c.u + 0x7FFFu + ((c.u >> 16) & 1u);   // RNE
  return (uint16_t)(r >> 16);
}

// ---- weights f32 -> bf16 (wqkv and wout merged; outputs are contiguous in ws)
__global__ __launch_bounds__(256) void cvtw_kernel(const float* __restrict__ wq,
                                                   const float* __restrict__ wo,
                                                   uint16_t* __restrict__ out) {
  int i = (blockIdx.x * 256 + threadIdx.x) * 8;       // grid 128 -> 262144 elems
  const float* src = (i < 196608) ? (wq + i) : (wo + (i - 196608));
  f32x4 a = *(const f32x4*)src;
  f32x4 b = *(const f32x4*)(src + 4);
  short8 v;
  v[0] = (short)f2bf(a[0]); v[1] = (short)f2bf(a[1]);
  v[2] = (short)f2bf(a[2]); v[3] = (short)f2bf(a[3]);
  v[4] = (short)f2bf(b[0]); v[5] = (short)f2bf(b[1]);
  v[6] = (short)f2bf(b[2]); v[7] = (short)f2bf(b[3]);
  *(short8*)(out + i) = v;
}

// ---- bias+mask table, transposed+interleaved: bm[wd][head][kk][a(16)][ni(4)]
__global__ __launch_bounds__(256) void bias_kernel(const float* __restrict__ pe,
                                                   float* __restrict__ bm) {
  int bx = blockIdx.x;              // wd*8 + head
  int wd = bx >> 3, head = bx & 7;
  int hw = wd >> 3, ww = wd & 7;
  int tid = threadIdx.x;
  int kk = tid >> 2, a0 = (tid & 3) * 4;
  int jy = kk >> 3, jx = kk & 7;
  int hj = hw * 8 + jy, xj = ww * 8 + jx;
  int rj = (hj >= 60 ? 2 : (hj >= 56 ? 1 : 0)) * 3 + (xj >= 60 ? 2 : (xj >= 56 ? 1 : 0));
  float* dst = bm + (size_t)bx * 4096 + kk * 64 + a0 * 4;
  for (int aa = 0; aa < 4; ++aa) {
    int a = a0 + aa;
    f32x4 v;
#pragma unroll
    for (int ni = 0; ni < 4; ++ni) {
      int i = ni * 16 + a;
      int iy = i >> 3, ix = i & 7;
      int hi = hw * 8 + iy, xi = ww * 8 + ix;
      int ri = (hi >= 60 ? 2 : (hi >= 56 ? 1 : 0)) * 3 + (xi >= 60 ? 2 : (xi >= 56 ? 1 : 0));
      v[ni] = (ri != rj) ? -1e30f : pe[head * 225 + (iy - jy + 7) * 15 + (ix - jx + 7)];
    }
    *(f32x4*)(dst + aa * 4) = v;
  }
}

// ---- FUSED cvtx + QKV GEMM.
//      One block per 128-token m-tile. A staged once into 64KB swizzled LDS.
//      B fragments read global->VGPR (wq L2-resident). One barrier total.
__global__ __launch_bounds__(256, 2) void qkv_kernel(
    const float* __restrict__ x, const uint16_t* __restrict__ wq,
    const float* __restrict__ bqkv,
    uint16_t* __restrict__ qws, uint16_t* __restrict__ kws, uint16_t* __restrict__ vws) {
  __shared__ uint16_t sm[36864];                 // 72 KB: A 64 KB + epi 8 KB
  uint16_t* As = sm;                             // [8 ks][128 row][32 k], swizzled
  const int tid = threadIdx.x, lane = tid & 63, wv = tid >> 6;
  const int quad = lane >> 4, l15 = lane & 15;
  const int m0 = blockIdx.x * 128;
  uint16_t* epi = sm + 32768 + wv * 1024;        // 2 KB/wave, wave-private

  // ---- stage A: roll(-4,-4)+window gather from f32, convert, swizzled ds_write
  {
    const int rl = tid >> 3;                     // 32 rows per pass
    const int cg = tid & 7;                      // 8 threads per row
    for (int pass = 0; pass < 4; ++pass) {
      int row = pass * 32 + rl;
      int token = m0 + row;
      int w = token >> 6, t = token & 63;
      int b = w >> 6, wd = w & 63;
      int h = (wd >> 3) * 8 + (t >> 3);
      int xx = (wd & 7) * 8 + (t & 7);
      const float* sp = x + (size_t)(b * 4096 + (((h + 4) & 63) << 6) + ((xx + 4) & 63)) * 256;
      int psw = (row >> 1) & 3;
#pragma unroll
      for (int j = 0; j < 4; ++j) {
        int c0 = cg * 8 + j * 64;
        f32x4 a = *(const f32x4*)(sp + c0);
        f32x4 d = *(const f32x4*)(sp + c0 + 4);
        short8 v;
        v[0] = (short)f2bf(a[0]); v[1] = (short)f2bf(a[1]);
        v[2] = (short)f2bf(a[2]); v[3] = (short)f2bf(a[3]);
        v[4] = (short)f2bf(d[0]); v[5] = (short)f2bf(d[1]);
        v[6] = (short)f2bf(d[2]); v[7] = (short)f2bf(d[3]);
        int ks = c0 >> 5, g = (c0 >> 3) & 3;
        *(short8*)&As[(ks * 128 + row) * 32 + (g ^ psw) * 8] = v;
      }
    }
  }

  const int wm = (wv & 1) * 64, wn = (wv >> 1) * 64;
  const int fsw = (quad ^ ((l15 >> 1) & 3)) * 8; // conflict-free frag granule
  const int tb = m0 + wm;
  f32x4 zero = {0.f, 0.f, 0.f, 0.f};

  __syncthreads();                               // A resident (only barrier)

  for (int nt = 0; nt < 6; ++nt) {
    const int n0 = nt * 128;
    // per-lane B row base: row = n0+wn+ni*16+l15, 16B chunk at ks*32+quad*8
    const uint16_t* bbase = wq + (size_t)(n0 + wn + l15) * 256 + quad * 8;

    short8 bfr[2][4];
#pragma unroll
    for (int ni = 0; ni < 4; ++ni)
      bfr[0][ni] = *(const short8*)(bbase + ni * 4096);

    f32x4 acc[4][4];
#pragma unroll
    for (int mi = 0; mi < 4; ++mi)
#pragma unroll
      for (int ni = 0; ni < 4; ++ni) acc[mi][ni] = zero;

#pragma unroll
    for (int ks = 0; ks < 8; ++ks) {
      const int cur = ks & 1;
      if (ks < 7) {                              // prefetch next k-step B frags
#pragma unroll
        for (int ni = 0; ni < 4; ++ni)
          bfr[cur ^ 1][ni] = *(const short8*)(bbase + ni * 4096 + (ks + 1) * 32);
      }
      short8 af[4];
#pragma unroll
      for (int mi = 0; mi < 4; ++mi)
        af[mi] = *(const short8*)&As[(ks * 128 + wm + mi * 16 + l15) * 32 + fsw];
#pragma unroll
      for (int mi = 0; mi < 4; ++mi)
#pragma unroll
        for (int ni = 0; ni < 4; ++ni)
          acc[mi][ni] = __builtin_amdgcn_mfma_f32_16x16x32_bf16(af[mi], bfr[cur][ni], acc[mi][ni], 0, 0, 0);
    }

    // ---- epilogue: wave-private 2KB LDS slice transpose, no barriers
    float bq4[4];
#pragma unroll
    for (int ni = 0; ni < 4; ++ni) bq4[ni] = bqkv[n0 + wn + ni * 16 + l15];
    const int ng0 = n0 + wn;                     // 64-aligned, single section
    const int sct = ng0 >> 8;                    // 0=q, 1=k, 2=v

    if (sct < 2) {
      uint16_t* dst = (sct == 0) ? qws : kws;
#pragma unroll
      for (int mi = 0; mi < 4; ++mi) {           // 16 t-rows per pass
#pragma unroll
        for (int ni = 0; ni < 4; ++ni)
#pragma unroll
          for (int r = 0; r < 4; ++r) {
            int tl = quad * 4 + r, t = mi * 16 + tl;
            int n = ni * 16 + l15;
            epi[tl * 64 + ((((n >> 3) ^ (t & 7)) << 3) | (n & 7))] =
                f2bf(acc[mi][ni][r] + bq4[ni]);
          }
#pragma unroll
        for (int cc = 0; cc < 2; ++cc) {
          int chunk = cc * 64 + lane;
          int trl = chunk >> 3, part = chunk & 7;
          int t = mi * 16 + trl;
          short8 v = *(const short8*)&epi[trl * 64 + ((part ^ (t & 7)) << 3)];
          int tok = tb + t, w = tok >> 6, tt = tok & 63;
          int ng = ng0 + part * 8, hd = (ng >> 5) & 7, d = ng & 31;
          *(short8*)&dst[(size_t)((w * 8 + hd) * 64 + tt) * 32 + d] = v;
        }
      }
    } else {
      // v: [d][t] (transposed) -> b64-packed LDS writes along t
#pragma unroll
      for (int ni = 0; ni < 4; ++ni) {           // 16 d-rows per pass
        int n = ni * 16 + l15;
#pragma unroll
        for (int mi = 0; mi < 4; ++mi) {
          int t0 = mi * 16 + quad * 4;
          s16x4 pv;
          pv[0] = (short)f2bf(acc[mi][ni][0] + bq4[ni]);
          pv[1] = (short)f2bf(acc[mi][ni][1] + bq4[ni]);
          pv[2] = (short)f2bf(acc[mi][ni][2] + bq4[ni]);
          pv[3] = (short)f2bf(acc[mi][ni][3] + bq4[ni]);
          *(s16x4*)&epi[l15 * 64 + ((((t0 >> 3) ^ (n & 7)) << 3) | (t0 & 7))] = pv;
        }
#pragma unroll
        for (int cc = 0; cc < 2; ++cc) {
          int chunk = cc * 64 + lane;
          int drl = chunk >> 3, part = chunk & 7;
          int dr = ni * 16 + drl;
          short8 v = *(const short8*)&epi[drl * 64 + ((part ^ (dr & 7)) << 3)];
          int ng = ng0 + dr, hd = (ng >> 5) & 7, d = ng & 31;
          int tok = tb + part * 8, w = tok >> 6, t = tok & 63;
          *(short8*)&vws[(size_t)((w * 8 + hd) * 32 + d) * 64 + t] = v;
        }
      }
    }
  }
}

// ---- attention: one wave per (window, head). S^T = K*Q^T, column softmax,
//      P via per-wave LDS, O = P*V, write AO[token][256] bf16. No barriers.
__global__ __launch_bounds__(256) void attn_kernel(
    const uint16_t* __restrict__ qws, const uint16_t* __restrict__ kws,
    const uint16_t* __restrict__ vws, const float* __restrict__ bm,
    uint16_t* __restrict__ ao) {
  __shared__ uint16_t P[4][4096];                // 8 KB per wave
  const int tid = threadIdx.x, lane = tid & 63, wv = tid >> 6;
  const int quad = lane >> 4, l15 = lane & 15;
  const int gid = blockIdx.x * 4 + wv;
  const int w = gid >> 3, head = gid & 7;
  const uint16_t* qb = qws + (size_t)(w * 8 + head) * 2048;
  const uint16_t* kb = kws + (size_t)(w * 8 + head) * 2048;
  const uint16_t* vb = vws + (size_t)(w * 8 + head) * 2048;
  const float* bmh = bm + (size_t)((w & 63) * 8 + head) * 4096;
  f32x4 zero = {0.f, 0.f, 0.f, 0.f};

  short8 ak[4], bq[4];
#pragma unroll
  for (int mi = 0; mi < 4; ++mi)
    ak[mi] = *(const short8*)&kb[(mi * 16 + l15) * 32 + quad * 8];
#pragma unroll
  for (int ni = 0; ni < 4; ++ni)
    bq[ni] = *(const short8*)&qb[(ni * 16 + l15) * 32 + quad * 8];

  f32x4 s[4][4];                                 // S^T: row kk, col q
#pragma unroll
  for (int mi = 0; mi < 4; ++mi)
#pragma unroll
    for (int ni = 0; ni < 4; ++ni)
      s[mi][ni] = __builtin_amdgcn_mfma_f32_16x16x32_bf16(ak[mi], bq[ni], zero, 0, 0, 0);

  // scale + bias (mask folded): coalesced f32x4 from interleaved table
#pragma unroll
  for (int mi = 0; mi < 4; ++mi)
#pragma unroll
    for (int r = 0; r < 4; ++r) {
      int kk = mi * 16 + quad * 4 + r;
      f32x4 b4 = *(const f32x4*)&bmh[kk * 64 + l15 * 4];
#pragma unroll
      for (int ni = 0; ni < 4; ++ni)
        s[mi][ni][r] = s[mi][ni][r] * SCALE + b4[ni];
    }

  // softmax per column q: 16 in-lane values + 2 shfls
#pragma unroll
  for (int ni = 0; ni < 4; ++ni) {
    float mx = s[0][ni][0];
#pragma unroll
    for (int mi = 0; mi < 4; ++mi)
#pragma unroll
      for (int r = 0; r < 4; ++r) mx = fmaxf(mx, s[mi][ni][r]);
    mx = fmaxf(mx, __shfl_xor(mx, 16, 64));
    mx = fmaxf(mx, __shfl_xor(mx, 32, 64));
    float sum = 0.f;
#pragma unroll
    for (int mi = 0; mi < 4; ++mi)
#pragma unroll
      for (int r = 0; r < 4; ++r) {
        float e = __expf(s[mi][ni][r] - mx);
        s[mi][ni][r] = e;
        sum += e;
      }
    sum += __shfl_xor(sum, 16, 64);
    sum += __shfl_xor(sum, 32, 64);
    float inv = 1.f / sum;
#pragma unroll
    for (int mi = 0; mi < 4; ++mi)
#pragma unroll
      for (int r = 0; r < 4; ++r) s[mi][ni][r] *= inv;
  }

  // P[q][kk] bf16, swizzled, packed-pair writes (intra-wave, no barrier)
  uint16_t* Pw = P[wv];
#pragma unroll
  for (int mi = 0; mi < 4; ++mi)
#pragma unroll
    for (int ni = 0; ni < 4; ++ni)
#pragma unroll
      for (int rp = 0; rp < 2; ++rp) {
        int kk = mi * 16 + quad * 4 + rp * 2;
        int q = ni * 16 + l15;
        uint32_t pk = (uint32_t)f2bf(s[mi][ni][rp * 2]) |
                      ((uint32_t)f2bf(s[mi][ni][rp * 2 + 1]) << 16);
        *(uint32_t*)&Pw[q * 64 + ((((kk >> 3) ^ (q & 7)) << 3) | (kk & 7))] = pk;
      }

  // O = P @ V (V stored [d][t] = B-operand layout)
  f32x4 o[4][2];
#pragma unroll
  for (int mi = 0; mi < 4; ++mi) { o[mi][0] = zero; o[mi][1] = zero; }
#pragma unroll
  for (int ki = 0; ki < 2; ++ki) {
    short8 vf0 = *(const short8*)&vb[(l15) * 64 + ki * 32 + quad * 8];
    short8 vf1 = *(const short8*)&vb[(16 + l15) * 64 + ki * 32 + quad * 8];
#pragma unroll
    for (int mi = 0; mi < 4; ++mi) {
      int q = mi * 16 + l15;
      short8 pa = *(const short8*)&Pw[q * 64 + (((ki * 4 + quad) ^ (q & 7)) << 3)];
      o[mi][0] = __builtin_amdgcn_mfma_f32_16x16x32_bf16(pa, vf0, o[mi][0], 0, 0, 0);
      o[mi][1] = __builtin_amdgcn_mfma_f32_16x16x32_bf16(pa, vf1, o[mi][1], 0, 0, 0);
    }
  }
#pragma unroll
  for (int mi = 0; mi < 4; ++mi)
#pragma unroll
    for (int ni = 0; ni < 2; ++ni)
#pragma unroll
      for (int r = 0; r < 4; ++r) {
        int t = mi * 16 + quad * 4 + r;
        ao[(size_t)(w * 64 + t) * 256 + head * 32 + ni * 16 + l15] = f2bf(o[mi][ni][r]);
      }
}

// ---- out-proj GEMM: out[131072,256] = AO @ wo^T + b, + merge/inv-roll scatter
//      Zero LDS, zero barriers: A and B fragments loaded global->VGPR.
//      n-loop internal -> AO fetched once; wo is L2-resident.
__global__ __launch_bounds__(256) void oproj_kernel(
    const uint16_t* __restrict__ aob, const uint16_t* __restrict__ wo,
    const float* __restrict__ bout, float* __restrict__ out) {
  const int tid = threadIdx.x, lane = tid & 63, wv = tid >> 6;
  const int quad = lane >> 4, l15 = lane & 15;
  const int m0 = blockIdx.x * 128;
  const int wm = (wv & 1) * 64, wn = (wv >> 1) * 64;
  f32x4 zero = {0.f, 0.f, 0.f, 0.f};

  // per-lane A row base: row = m0+wm+mi*16+l15, 16B chunk at ks*32+quad*8
  const uint16_t* abase = aob + (size_t)(m0 + wm + l15) * 256 + quad * 8;

  for (int nt = 0; nt < 2; ++nt) {
    const uint16_t* bbase = wo + (size_t)(nt * 128 + wn + l15) * 256 + quad * 8;

    short8 afr[2][4], bfr[2][4];
#pragma unroll
    for (int mi = 0; mi < 4; ++mi)
      afr[0][mi] = *(const short8*)(abase + mi * 4096);
#pragma unroll
    for (int ni = 0; ni < 4; ++ni)
      bfr[0][ni] = *(const short8*)(bbase + ni * 4096);

    f32x4 acc[4][4];
#pragma unroll
    for (int mi = 0; mi < 4; ++mi)
#pragma unroll
      for (int ni = 0; ni < 4; ++ni) acc[mi][ni] = zero;

#pragma unroll
    for (int ks = 0; ks < 8; ++ks) {
      const int cur = ks & 1;
      if (ks < 7) {
#pragma unroll
        for (int mi = 0; mi < 4; ++mi)
          afr[cur ^ 1][mi] = *(const short8*)(abase + mi * 4096 + (ks + 1) * 32);
#pragma unroll
        for (int ni = 0; ni < 4; ++ni)
          bfr[cur ^ 1][ni] = *(const short8*)(bbase + ni * 4096 + (ks + 1) * 32);
      }
#pragma unroll
      for (int mi = 0; mi < 4; ++mi)
#pragma unroll
        for (int ni = 0; ni < 4; ++ni)
          acc[mi][ni] = __builtin_amdgcn_mfma_f32_16x16x32_bf16(afr[cur][mi], bfr[cur][ni], acc[mi][ni], 0, 0, 0);
    }

    float bo4[4];
#pragma unroll
    for (int ni = 0; ni < 4; ++ni) bo4[ni] = bout[nt * 128 + wn + ni * 16 + l15];
#pragma unroll
    for (int mi = 0; mi < 4; ++mi) {
      int mb = m0 + wm + mi * 16 + quad * 4;
      int w = mb >> 6, t0 = mb & 63;
      int b = w >> 6, wd = w & 63;
      int hw2 = wd >> 3, ww2 = wd & 7;
#pragma unroll
      for (int r = 0; r < 4; ++r) {
        int t = t0 + r;
        int h = hw2 * 8 + (t >> 3), xx = ww2 * 8 + (t & 7);
        int row = (((h + 4) & 63) << 6) | ((xx + 4) & 63);   // merge + inverse roll
        float* op = out + ((size_t)b * 4096 + row) * 256 + nt * 128 + wn;
#pragma unroll
        for (int ni = 0; ni < 4; ++ni) op[ni * 16 + l15] = acc[mi][ni][r] + bo4[ni];
      }
    }
  }
}

extern "C" void kernel_launch(void* const* d_in, const int* in_sizes, int n_in,
                              void* d_out, int out_size, void* d_ws, size_t ws_size,
                              hipStream_t stream) {
  const float* x = (const float*)d_in[0];
  const float* w_qkv = (const float*)d_in[1];
  const float* b_qkv = (const float*)d_in[2];
  const float* w_out = (const float*)d_in[3];
  const float* b_out = (const float*)d_in[4];
  const float* pos_enc = (const float*)d_in[5];
  float* out = (float*)d_out;

  uint8_t* ws = (uint8_t*)d_ws;
  uint16_t* aob = (uint16_t*)(ws);                 // 67,108,864 B (AO)
  uint16_t* wqb = (uint16_t*)(ws + 67108864);      //    393,216 B
  uint16_t* wob = (uint16_t*)(ws + 67502080);      //    131,072 B (contig w/ wqb)
  float*    bmt = (float*)   (ws + 67633152);      //  8,388,608 B
  uint16_t* qws = (uint16_t*)(ws + 76021760);      // 67,108,864 B
  uint16_t* kws = (uint16_t*)(ws + 143130624);     // 67,108,864 B
  uint16_t* vws = (uint16_t*)(ws + 210239488);     // 67,108,864 B -> 277,348,352 B

  cvtw_kernel<<<128, 256, 0, stream>>>(w_qkv, w_out, wqb);
  bias_kernel<<<512, 256, 0, stream>>>(pos_enc, bmt);
  qkv_kernel<<<1024, 256, 0, stream>>>(x, wqb, b_qkv, qws, kws, vws);
  attn_kernel<<<4096, 256, 0, stream>>>(qws, kws, vws, bmt, aob);
  oproj_kernel<<<1024, 256, 0, stream>>>(aob, wob, b_out, out);
}

// Round 6
// 367.669 us; speedup vs baseline: 1.2935x; 1.2935x over previous
//
#include <hip/hip_runtime.h>
#include <stdint.h>

// ---------------------------------------------------------------------------
// ShiftedWindowAttention: B=32, H=W=64, C=256, heads=8, hd=32, ws=8, shift=4.
// Pipeline (v5.1 = v5 with section-stride fix 131072->65536):
//   cvtw  (weights f32->bf16, merged wqkv+wout)
//   bias  (pos_enc -> transposed/interleaved bias+mask table, f32)
//   wattn (FUSED cvtx+qkv+attention, one block per (window, head-half):
//          A 64x256 staged once (32KB swizzled LDS, reused as P-scratch);
//          per-wave qkv GEMM N=96 with B global->VGPR, ZERO K-loop barriers;
//          q/k/v -> wave-private LDS (48KB); attn (QK^T, bias, softmax,
//          P roundtrip, PV) all from LDS; AO[token][256] bf16 out.
//          2 barriers total. 80KB LDS -> 2 blocks/CU.)
//   oproj (GEMM 131072x256x256 + merge/inv-roll scatter, v3 dbuf form)
// ---------------------------------------------------------------------------

typedef short short8 __attribute__((ext_vector_type(8)));
typedef short s16x4 __attribute__((ext_vector_type(4)));
typedef float f32x4 __attribute__((ext_vector_type(4)));

typedef __attribute__((address_space(1))) uint32_t g_u32;
typedef __attribute__((address_space(3))) uint32_t l_u32;

#define SCALE 0.17677669529663687f

__device__ __forceinline__ uint16_t f2bf(float f) {
  union { float f; uint32_t u; } c; c.f = f;
  uint32_t r = c.u + 0x7FFFu + ((c.u >> 16) & 1u);   // RNE
  return (uint16_t)(r >> 16);
}

__device__ __forceinline__ void g2lds16(const void* g, void* l) {
  __builtin_amdgcn_global_load_lds((const g_u32*)g, (l_u32*)l, 16, 0, 0);
}

// ---- weights f32 -> bf16 (wqkv and wout merged; outputs contiguous in ws)
__global__ __launch_bounds__(256) void cvtw_kernel(const float* __restrict__ wq,
                                                   const float* __restrict__ wo,
                                                   uint16_t* __restrict__ out) {
  int i = (blockIdx.x * 256 + threadIdx.x) * 8;       // grid 128 -> 262144 elems
  const float* src = (i < 196608) ? (wq + i) : (wo + (i - 196608));
  f32x4 a = *(const f32x4*)src;
  f32x4 b = *(const f32x4*)(src + 4);
  short8 v;
  v[0] = (short)f2bf(a[0]); v[1] = (short)f2bf(a[1]);
  v[2] = (short)f2bf(a[2]); v[3] = (short)f2bf(a[3]);
  v[4] = (short)f2bf(b[0]); v[5] = (short)f2bf(b[1]);
  v[6] = (short)f2bf(b[2]); v[7] = (short)f2bf(b[3]);
  *(short8*)(out + i) = v;
}

// ---- bias+mask table, transposed+interleaved: bm[wd][head][kk][a(16)][ni(4)]
__global__ __launch_bounds__(256) void bias_kernel(const float* __restrict__ pe,
                                                   float* __restrict__ bm) {
  int bx = blockIdx.x;              // wd*8 + head
  int wd = bx >> 3, head = bx & 7;
  int hw = wd >> 3, ww = wd & 7;
  int tid = threadIdx.x;
  int kk = tid >> 2, a0 = (tid & 3) * 4;
  int jy = kk >> 3, jx = kk & 7;
  int hj = hw * 8 + jy, xj = ww * 8 + jx;
  int rj = (hj >= 60 ? 2 : (hj >= 56 ? 1 : 0)) * 3 + (xj >= 60 ? 2 : (xj >= 56 ? 1 : 0));
  float* dst = bm + (size_t)bx * 4096 + kk * 64 + a0 * 4;
  for (int aa = 0; aa < 4; ++aa) {
    int a = a0 + aa;
    f32x4 v;
#pragma unroll
    for (int ni = 0; ni < 4; ++ni) {
      int i = ni * 16 + a;
      int iy = i >> 3, ix = i & 7;
      int hi = hw * 8 + iy, xi = ww * 8 + ix;
      int ri = (hi >= 60 ? 2 : (hi >= 56 ? 1 : 0)) * 3 + (xi >= 60 ? 2 : (xi >= 56 ? 1 : 0));
      v[ni] = (ri != rj) ? -1e30f : pe[head * 225 + (iy - jy + 7) * 15 + (ix - jx + 7)];
    }
    *(f32x4*)(dst + aa * 4) = v;
  }
}

// ---- FUSED cvtx + qkv + attention. One block per (window, head-half).
//      4 waves; wave = one head. 80 KB LDS -> 2 blocks/CU.
__global__ __launch_bounds__(256, 2) void wattn_kernel(
    const float* __restrict__ x, const uint16_t* __restrict__ wq,
    const float* __restrict__ bqkv, const float* __restrict__ bm,
    uint16_t* __restrict__ ao) {
  __shared__ uint16_t sm[40960];                 // 80 KB
  uint16_t* As = sm;                             // [8 ks][64 t][32 k] swizzled; later P[4][4096]
  const int tid = threadIdx.x, lane = tid & 63, wv = tid >> 6;
  const int quad = lane >> 4, l15 = lane & 15;
  const int b = blockIdx.x;
  const int w = ((b >> 4) << 3) + (b & 7);       // window (pairs 8 apart: same XCD)
  const int hh = (b >> 3) & 1;                   // head half
  const int h = hh * 4 + wv;                     // this wave's head
  const int wd = w & 63, bb = w >> 6;
  f32x4 zero = {0.f, 0.f, 0.f, 0.f};

  // ---- stage A: roll(-4,-4)+window gather f32 -> bf16 -> swizzled LDS (32KB)
  {
    const int rl = tid >> 3;                     // 32 rows per pass
    const int cg = tid & 7;                      // 8 threads per row
#pragma unroll
    for (int pass = 0; pass < 2; ++pass) {
      int row = pass * 32 + rl;                  // token within window
      int hy = (wd >> 3) * 8 + (row >> 3);
      int xx = (wd & 7) * 8 + (row & 7);
      const float* sp = x + (size_t)(bb * 4096 + (((hy + 4) & 63) << 6) + ((xx + 4) & 63)) * 256;
      int psw = (row >> 1) & 3;
#pragma unroll
      for (int j = 0; j < 4; ++j) {
        int c0 = cg * 8 + j * 64;
        f32x4 a = *(const f32x4*)(sp + c0);
        f32x4 d = *(const f32x4*)(sp + c0 + 4);
        short8 v;
        v[0] = (short)f2bf(a[0]); v[1] = (short)f2bf(a[1]);
        v[2] = (short)f2bf(a[2]); v[3] = (short)f2bf(a[3]);
        v[4] = (short)f2bf(d[0]); v[5] = (short)f2bf(d[1]);
        v[6] = (short)f2bf(d[2]); v[7] = (short)f2bf(d[3]);
        int ks = c0 >> 5, g = (c0 >> 3) & 3;
        *(short8*)&As[(ks * 64 + row) * 32 + ((g ^ psw) << 3)] = v;
      }
    }
  }

  const int fsw = (quad ^ ((l15 >> 1) & 3)) << 3;  // conflict-free frag granule
  uint16_t* qk = sm + 16384 + wv * 6144;           // wave-private: q|k|v(+4096)

  // B rows for this wave: sec*256 + h*32 + (ni&1)*16 + l15  (sec = ni>>1)
  // section stride = 256 rows * 256 cols = 65536 elements
  const uint16_t* bb0 = wq + (size_t)(h * 32 + l15) * 256 + quad * 8;

  short8 bfr[2][6];
#pragma unroll
  for (int ni = 0; ni < 6; ++ni)
    bfr[0][ni] = *(const short8*)(bb0 + (ni >> 1) * 65536 + (ni & 1) * 4096);

  f32x4 acc[4][6];
#pragma unroll
  for (int mi = 0; mi < 4; ++mi)
#pragma unroll
    for (int ni = 0; ni < 6; ++ni) acc[mi][ni] = zero;

  __syncthreads();                               // barrier 1: A resident

#pragma unroll
  for (int ks = 0; ks < 8; ++ks) {
    const int cur = ks & 1;
    if (ks < 7) {                                // register prefetch next k-step
#pragma unroll
      for (int ni = 0; ni < 6; ++ni)
        bfr[cur ^ 1][ni] = *(const short8*)(bb0 + (ni >> 1) * 65536 + (ni & 1) * 4096 + (ks + 1) * 32);
    }
    short8 af[4];
#pragma unroll
    for (int mi = 0; mi < 4; ++mi)
      af[mi] = *(const short8*)&As[(ks * 64 + mi * 16 + l15) * 32 + fsw];
#pragma unroll
    for (int mi = 0; mi < 4; ++mi)
#pragma unroll
      for (int ni = 0; ni < 6; ++ni)
        acc[mi][ni] = __builtin_amdgcn_mfma_f32_16x16x32_bf16(af[mi], bfr[cur][ni], acc[mi][ni], 0, 0, 0);
  }

  // ---- epilogue: bias add, write q/k ([t][32] swizzled) + v ([d][t] swizzled)
  //      into wave-private LDS. No barrier needed.
  float bqv[6];
#pragma unroll
  for (int ni = 0; ni < 6; ++ni)
    bqv[ni] = bqkv[(ni >> 1) * 256 + h * 32 + (ni & 1) * 16 + l15];

#pragma unroll
  for (int ni = 0; ni < 4; ++ni) {               // q (ni 0,1), k (ni 2,3)
    uint16_t* dst = qk + (ni >> 1) * 2048;
    int d = (ni & 1) * 16 + l15, dg = d >> 3;
#pragma unroll
    for (int mi = 0; mi < 4; ++mi)
#pragma unroll
      for (int r = 0; r < 4; ++r) {
        int t = mi * 16 + quad * 4 + r;
        dst[t * 32 + (((dg ^ ((t >> 1) & 3)) << 3) | (d & 7))] =
            f2bf(acc[mi][ni][r] + bqv[ni]);
      }
  }
  {
    uint16_t* vdst = qk + 4096;                  // v: [d][64 t], t-granule XOR
#pragma unroll
    for (int ni = 4; ni < 6; ++ni) {
      int d = (ni - 4) * 16 + l15;
#pragma unroll
      for (int mi = 0; mi < 4; ++mi) {
        int t0 = mi * 16 + quad * 4;
        s16x4 pv;
        pv[0] = (short)f2bf(acc[mi][ni][0] + bqv[ni]);
        pv[1] = (short)f2bf(acc[mi][ni][1] + bqv[ni]);
        pv[2] = (short)f2bf(acc[mi][ni][2] + bqv[ni]);
        pv[3] = (short)f2bf(acc[mi][ni][3] + bqv[ni]);
        *(s16x4*)&vdst[d * 64 + (t0 ^ ((d & 7) << 3))] = pv;
      }
    }
  }

  __syncthreads();                               // barrier 2: A dead, qkv ready

  // ---- attention (wave-private): S^T = K*Q^T, column softmax, P LDS
  //      roundtrip (A region), O = P*V, AO write.
  const uint16_t* qb2 = qk;
  const uint16_t* kb2 = qk + 2048;
  const uint16_t* vb2 = qk + 4096;
  const float* bmh = bm + ((size_t)wd * 8 + h) * 4096;

  short8 ak[4], bq[4];
#pragma unroll
  for (int mi = 0; mi < 4; ++mi)
    ak[mi] = *(const short8*)&kb2[(mi * 16 + l15) * 32 + fsw];
#pragma unroll
  for (int ni = 0; ni < 4; ++ni)
    bq[ni] = *(const short8*)&qb2[(ni * 16 + l15) * 32 + fsw];

  f32x4 s[4][4];                                 // S^T: row kk, col q
#pragma unroll
  for (int mi = 0; mi < 4; ++mi)
#pragma unroll
    for (int ni = 0; ni < 4; ++ni)
      s[mi][ni] = __builtin_amdgcn_mfma_f32_16x16x32_bf16(ak[mi], bq[ni], zero, 0, 0, 0);

#pragma unroll
  for (int mi = 0; mi < 4; ++mi)
#pragma unroll
    for (int r = 0; r < 4; ++r) {
      int kk = mi * 16 + quad * 4 + r;
      f32x4 b4 = *(const f32x4*)&bmh[kk * 64 + l15 * 4];
#pragma unroll
      for (int ni = 0; ni < 4; ++ni)
        s[mi][ni][r] = s[mi][ni][r] * SCALE + b4[ni];
    }

  // softmax per column q: 16 in-lane values + 2 shfls
#pragma unroll
  for (int ni = 0; ni < 4; ++ni) {
    float mx = s[0][ni][0];
#pragma unroll
    for (int mi = 0; mi < 4; ++mi)
#pragma unroll
      for (int r = 0; r < 4; ++r) mx = fmaxf(mx, s[mi][ni][r]);
    mx = fmaxf(mx, __shfl_xor(mx, 16, 64));
    mx = fmaxf(mx, __shfl_xor(mx, 32, 64));
    float sum = 0.f;
#pragma unroll
    for (int mi = 0; mi < 4; ++mi)
#pragma unroll
      for (int r = 0; r < 4; ++r) {
        float e = __expf(s[mi][ni][r] - mx);
        s[mi][ni][r] = e;
        sum += e;
      }
    sum += __shfl_xor(sum, 16, 64);
    sum += __shfl_xor(sum, 32, 64);
    float inv = 1.f / sum;
#pragma unroll
    for (int mi = 0; mi < 4; ++mi)
#pragma unroll
      for (int r = 0; r < 4; ++r) s[mi][ni][r] *= inv;
  }

  // P[q][kk] bf16, swizzled, packed-pair writes (wave-private A region)
  uint16_t* Pw = sm + wv * 4096;
#pragma unroll
  for (int mi = 0; mi < 4; ++mi)
#pragma unroll
    for (int ni = 0; ni < 4; ++ni)
#pragma unroll
      for (int rp = 0; rp < 2; ++rp) {
        int kk = mi * 16 + quad * 4 + rp * 2;
        int q = ni * 16 + l15;
        uint32_t pk = (uint32_t)f2bf(s[mi][ni][rp * 2]) |
                      ((uint32_t)f2bf(s[mi][ni][rp * 2 + 1]) << 16);
        *(uint32_t*)&Pw[q * 64 + ((((kk >> 3) ^ (q & 7)) << 3) | (kk & 7))] = pk;
      }

  // O = P @ V (V in LDS [d][t], t-granule XOR swizzle)
  f32x4 o[4][2];
#pragma unroll
  for (int mi = 0; mi < 4; ++mi) { o[mi][0] = zero; o[mi][1] = zero; }
#pragma unroll
  for (int ki = 0; ki < 2; ++ki) {
    int tc = ki * 32 + quad * 8;
    short8 vf0 = *(const short8*)&vb2[l15 * 64 + (tc ^ ((l15 & 7) << 3))];
    short8 vf1 = *(const short8*)&vb2[(16 + l15) * 64 + (tc ^ ((l15 & 7) << 3))];
#pragma unroll
    for (int mi = 0; mi < 4; ++mi) {
      int q = mi * 16 + l15;
      short8 pa = *(const short8*)&Pw[q * 64 + (((ki * 4 + quad) ^ (q & 7)) << 3)];
      o[mi][0] = __builtin_amdgcn_mfma_f32_16x16x32_bf16(pa, vf0, o[mi][0], 0, 0, 0);
      o[mi][1] = __builtin_amdgcn_mfma_f32_16x16x32_bf16(pa, vf1, o[mi][1], 0, 0, 0);
    }
  }
#pragma unroll
  for (int mi = 0; mi < 4; ++mi)
#pragma unroll
    for (int ni = 0; ni < 2; ++ni)
#pragma unroll
      for (int r = 0; r < 4; ++r) {
        int t = mi * 16 + quad * 4 + r;
        ao[(size_t)(w * 64 + t) * 256 + h * 32 + ni * 16 + l15] = f2bf(o[mi][ni][r]);
      }
}

// ---- out-proj GEMM: out[131072,256] = AO @ wo^T + b, + merge/inv-roll scatter
//      Double-buffered, top-barrier/issue-after scheme (v3, measured-good).
__global__ __launch_bounds__(256) void oproj_kernel(
    const uint16_t* __restrict__ aob, const uint16_t* __restrict__ wo,
    const float* __restrict__ bout, float* __restrict__ out) {
  __shared__ uint16_t sm[16384];                 // 32 KB: A dbuf 16 + B dbuf 16
  uint16_t* As = sm;                             // [2][128][32]
  uint16_t* Bs = sm + 8192;                      // [2][128][32]
  const int tid = threadIdx.x, lane = tid & 63, wv = tid >> 6;
  const int quad = lane >> 4, l15 = lane & 15;
  const int n0 = blockIdx.x * 128;
  const int m0 = blockIdx.y * 128;

  const int c0 = wv * 2, c1 = c0 + 1;
  const int perm = ((lane & 3) ^ ((lane >> 3) & 3)) * 8;
  const int fsw = (quad ^ ((l15 >> 1) & 3)) * 8;
  const uint16_t* ap0 = aob + (size_t)(m0 + c0 * 16 + (lane >> 2)) * 256 + perm;
  const uint16_t* ap1 = aob + (size_t)(m0 + c1 * 16 + (lane >> 2)) * 256 + perm;
  const uint16_t* bp0 = wo + (size_t)(n0 + c0 * 16 + (lane >> 2)) * 256 + perm;
  const uint16_t* bp1 = wo + (size_t)(n0 + c1 * 16 + (lane >> 2)) * 256 + perm;

  const int wm = (wv & 1) * 64, wn = (wv >> 1) * 64;
  f32x4 zero = {0.f, 0.f, 0.f, 0.f};
  f32x4 acc[4][4];
#pragma unroll
  for (int mi = 0; mi < 4; ++mi)
#pragma unroll
    for (int ni = 0; ni < 4; ++ni) acc[mi][ni] = zero;

  // prologue: ks=0 into buf0
  g2lds16(ap0, &As[c0 * 512]);
  g2lds16(ap1, &As[c1 * 512]);
  g2lds16(bp0, &Bs[c0 * 512]);
  g2lds16(bp1, &Bs[c1 * 512]);

#pragma unroll
  for (int ks = 0; ks < 8; ++ks) {
    __syncthreads();                             // drains loads issued a phase ago
    if (ks < 7) {
      int nb = ((ks + 1) & 1) * 4096, k0 = (ks + 1) * 32;
      g2lds16(ap0 + k0, &As[nb + c0 * 512]);
      g2lds16(ap1 + k0, &As[nb + c1 * 512]);
      g2lds16(bp0 + k0, &Bs[nb + c0 * 512]);
      g2lds16(bp1 + k0, &Bs[nb + c1 * 512]);
    }
    int buf = (ks & 1) * 4096;
    short8 af[4], bf[4];
#pragma unroll
    for (int mi = 0; mi < 4; ++mi)
      af[mi] = *(const short8*)&As[buf + (wm + mi * 16 + l15) * 32 + fsw];
#pragma unroll
    for (int ni = 0; ni < 4; ++ni)
      bf[ni] = *(const short8*)&Bs[buf + (wn + ni * 16 + l15) * 32 + fsw];
#pragma unroll
    for (int mi = 0; mi < 4; ++mi)
#pragma unroll
      for (int ni = 0; ni < 4; ++ni)
        acc[mi][ni] = __builtin_amdgcn_mfma_f32_16x16x32_bf16(af[mi], bf[ni], acc[mi][ni], 0, 0, 0);
  }

  float bo4[4];
#pragma unroll
  for (int ni = 0; ni < 4; ++ni) bo4[ni] = bout[n0 + wn + ni * 16 + l15];
#pragma unroll
  for (int mi = 0; mi < 4; ++mi) {
    int mb = m0 + wm + mi * 16 + quad * 4;
    int w = mb >> 6, t0 = mb & 63;
    int b = w >> 6, wd = w & 63;
    int hw2 = wd >> 3, ww2 = wd & 7;
#pragma unroll
    for (int r = 0; r < 4; ++r) {
      int t = t0 + r;
      int h = hw2 * 8 + (t >> 3), xx = ww2 * 8 + (t & 7);
      int row = (((h + 4) & 63) << 6) | ((xx + 4) & 63);   // merge + inverse roll
      float* op = out + ((size_t)b * 4096 + row) * 256 + n0 + wn;
#pragma unroll
      for (int ni = 0; ni < 4; ++ni) op[ni * 16 + l15] = acc[mi][ni][r] + bo4[ni];
    }
  }
}

extern "C" void kernel_launch(void* const* d_in, const int* in_sizes, int n_in,
                              void* d_out, int out_size, void* d_ws, size_t ws_size,
                              hipStream_t stream) {
  const float* x = (const float*)d_in[0];
  const float* w_qkv = (const float*)d_in[1];
  const float* b_qkv = (const float*)d_in[2];
  const float* w_out = (const float*)d_in[3];
  const float* b_out = (const float*)d_in[4];
  const float* pos_enc = (const float*)d_in[5];
  float* out = (float*)d_out;

  uint8_t* ws = (uint8_t*)d_ws;
  uint16_t* aob = (uint16_t*)(ws);                 // 67,108,864 B (AO)
  uint16_t* wqb = (uint16_t*)(ws + 67108864);      //    393,216 B
  uint16_t* wob = (uint16_t*)(ws + 67502080);      //    131,072 B (contig w/ wqb)
  float*    bmt = (float*)   (ws + 67633152);      //  8,388,608 B

  cvtw_kernel<<<128, 256, 0, stream>>>(w_qkv, w_out, wqb);
  bias_kernel<<<512, 256, 0, stream>>>(pos_enc, bmt);
  wattn_kernel<<<4096, 256, 0, stream>>>(x, wqb, b_qkv, bmt, aob);
  oproj_kernel<<<dim3(2, 1024), 256, 0, stream>>>(aob, wob, b_out, out);
}